// Round 4
// baseline (405.847 us; speedup 1.0000x reference)
//
#include <hip/hip_runtime.h>
#include <hip/hip_fp16.h>

// MemoryCore: p = softmax_k(keys @ q / sqrt(De)); mem = mo @ p; out = [mem; q_out], p
// B=8 T=4 De=128 Do=512 H=W=32 -> THW=4096 (k), HW=1024 (n)
//
// Pipeline (fp16 MFMA, m97-style global_load_lds staging, T2 swizzle):
//  1) prep: zero mem-region+Z; cast m_out->moH; transpose m_in->kH[b][thw][d],
//     q_in->qT[b][hw][d]  (one sectioned kernel)
//  2) gemm1: E_t[n][k] = exp(scale * kH@qT^T) fp16 (k-contiguous), Z[n] atomic
//  3) gemm2: out_mem += (moH @ E_t^T) / Z   (split-K x4, fp32 atomics, /Z folded)
//  4) finalize: p[k][n] = E_t^T / Z (LDS tile transpose) + q_out copy

typedef _Float16 f16x8 __attribute__((ext_vector_type(8)));
typedef _Float16 f16x4 __attribute__((ext_vector_type(4)));
typedef float    f32x4 __attribute__((ext_vector_type(4)));

static __device__ __forceinline__ f32x4 mfma16h(f16x8 a, f16x8 b, f32x4 c) {
  return __builtin_amdgcn_mfma_f32_16x16x32_f16(a, b, c, 0, 0, 0);
}

// global -> LDS direct DMA, 16B per lane. LDS dest = wave-uniform base + lane*16.
static __device__ __forceinline__ void gload16(const void* g, void* l) {
  __builtin_amdgcn_global_load_lds(
      (const __attribute__((address_space(1))) unsigned int*)(g),
      (__attribute__((address_space(3))) unsigned int*)(l),
      16, 0, 0);
}

// ---------------------------------------------------------------------------
// prep (sectioned):
//   blocks [0,512):    zero mem-region of out + Z
//   blocks [512,1024): cast m_out -> moH fp16
//   blocks [1024,2048): transpose m_in [32 slabs][128][1024] -> kH [.][1024][128]
//   blocks [2048,2304): transpose q_in [8 slabs][128][1024] -> qT [.][1024][128]
// ---------------------------------------------------------------------------
__global__ __launch_bounds__(256) void prep_kernel(
    const float* __restrict__ m_in, const float* __restrict__ m_out,
    const float* __restrict__ q_in, float* __restrict__ out,
    float* __restrict__ Z, _Float16* __restrict__ moH,
    _Float16* __restrict__ kH, _Float16* __restrict__ qT)
{
  __shared__ float T[64][65];
  const int bid = blockIdx.x, t = threadIdx.x;

  if (bid < 512) {                       // ---- zero mem region + Z
    const int NM = 1048576;              // mem f32x4 (8*512*1024/4)
    const f32x4 zv = {0.f, 0.f, 0.f, 0.f};
    for (int i = bid*256 + t; i < NM + 2048; i += 512*256) {
      if (i < NM) {
        const int b = i >> 17, rem = i & 131071;
        ((f32x4*)out)[(size_t)b*262144 + rem] = zv;
      } else {
        ((f32x4*)Z)[i - NM] = zv;
      }
    }
  } else if (bid < 1024) {               // ---- cast m_out -> moH
    for (int i = (bid-512)*256 + t; i < 2097152; i += 512*256) {
      f32x4 a = ((const f32x4*)m_out)[2*i], b = ((const f32x4*)m_out)[2*i+1];
      f16x8 v;
      v[0]=(_Float16)a[0]; v[1]=(_Float16)a[1]; v[2]=(_Float16)a[2]; v[3]=(_Float16)a[3];
      v[4]=(_Float16)b[0]; v[5]=(_Float16)b[1]; v[6]=(_Float16)b[2]; v[7]=(_Float16)b[3];
      ((f16x8*)moH)[i] = v;
    }
  } else {                               // ---- transpose+cast 64x64 tiles
    const float* src; _Float16* dst; int idx;
    if (bid < 2048) { idx = bid - 1024; src = m_in; dst = kH; }
    else            { idx = bid - 2048; src = q_in; dst = qT; }
    const int slab = idx >> 5, tile = idx & 31;
    const int tx = tile & 15, ty = tile >> 4;
    const int c0 = tx*64, r0 = ty*64;
    const float* s = src + (size_t)slab*131072;
    _Float16*    d = dst + (size_t)slab*131072;
    {
      const int rr = t >> 4, cq = t & 15;
      #pragma unroll
      for (int i = 0; i < 4; ++i) {
        f32x4 v = *(const f32x4*)(s + (size_t)(r0 + rr + 16*i)*1024 + c0 + cq*4);
        T[rr+16*i][cq*4+0] = v[0]; T[rr+16*i][cq*4+1] = v[1];
        T[rr+16*i][cq*4+2] = v[2]; T[rr+16*i][cq*4+3] = v[3];
      }
    }
    __syncthreads();
    {
      const int cl = t >> 2, rq = t & 3;
      #pragma unroll
      for (int u = 0; u < 2; ++u) {
        f16x8 v;
        #pragma unroll
        for (int j = 0; j < 8; ++j) v[j] = (_Float16)T[rq*16 + u*8 + j][cl];
        *(f16x8*)(d + (size_t)(c0 + cl)*128 + r0 + rq*16 + u*8) = v;
      }
    }
  }
}

// ---------------------------------------------------------------------------
// GEMM1: E_t[n][k] = exp(scale * (kH @ qT^T)[k][n]), Z[n] += col sums
// kH[b][4096][128], qT[b][1024][128] fp16. tile 128k x 128n, BK=64 over d
// ---------------------------------------------------------------------------
__global__ __launch_bounds__(256) void gemm1_kernel(
    const _Float16* __restrict__ kH, const _Float16* __restrict__ qT,
    _Float16* __restrict__ Et, float* __restrict__ Z) {
  const int b = blockIdx.z, n0 = blockIdx.x*128, k0 = blockIdx.y*128;
  const int tid = threadIdx.x, lane = tid & 63, wid = tid >> 6;
  const int wr = wid >> 1, wc = wid & 1;
  __shared__ __align__(16) _Float16 As[8192], Bs[8192];   // [128][64], swizzled

  const char* Ag = (const char*)(kH + (size_t)b*524288 + (size_t)k0*128); // row stride 256B
  const char* Bg = (const char*)(qT + (size_t)b*131072 + (size_t)n0*128);

  f32x4 acc[4][4] = {};
  const int srow = tid >> 3, ssl = tid & 7;

  for (int dc = 0; dc < 2; ++dc) {
    __syncthreads();
    #pragma unroll
    for (int c = 0; c < 4; ++c) {
      const int row = c*32 + srow;
      const int sg  = ssl ^ (row & 7);           // inverse-swizzled global source
      gload16(Ag + (size_t)row*256 + dc*128 + sg*16, As + c*2048 + wid*512);
      gload16(Bg + (size_t)row*256 + dc*128 + sg*16, Bs + c*2048 + wid*512);
    }
    __syncthreads();                              // drains vmcnt -> LDS ready
    #pragma unroll
    for (int kk = 0; kk < 2; ++kk) {
      f16x8 af[4], bf[4];
      #pragma unroll
      for (int mf = 0; mf < 4; ++mf) {
        const int row = wr*64 + mf*16 + (lane & 15);
        const int u   = kk*4 + (lane >> 4);
        af[mf] = *(const f16x8*)&As[row*64 + ((u ^ (row & 7)) << 3)];
      }
      #pragma unroll
      for (int nf = 0; nf < 4; ++nf) {
        const int row = wc*64 + nf*16 + (lane & 15);
        const int u   = kk*4 + (lane >> 4);
        bf[nf] = *(const f16x8*)&Bs[row*64 + ((u ^ (row & 7)) << 3)];
      }
      #pragma unroll
      for (int mf = 0; mf < 4; ++mf)
        #pragma unroll
        for (int nf = 0; nf < 4; ++nf)
          acc[mf][nf] = mfma16h(af[mf], bf[nf], acc[mf][nf]);
    }
  }

  const float scale = 0.088388347648318447f;   // 1/sqrt(128)
  float cs[4] = {0.f, 0.f, 0.f, 0.f};
  _Float16* Eb = Et + (size_t)b*4194304;
  #pragma unroll
  for (int nf = 0; nf < 4; ++nf) {
    const int n = n0 + wc*64 + nf*16 + (lane & 15);
    #pragma unroll
    for (int mf = 0; mf < 4; ++mf) {
      const int kb = k0 + wr*64 + mf*16 + ((lane >> 4) << 2);  // 4 consecutive k
      f16x4 v;
      #pragma unroll
      for (int r = 0; r < 4; ++r) {
        float e = __expf(acc[mf][nf][r] * scale);
        v[r] = (_Float16)e; cs[nf] += e;
      }
      *(f16x4*)(Eb + (size_t)n*4096 + kb) = v;   // 8B packed store
    }
  }
  #pragma unroll
  for (int nf = 0; nf < 4; ++nf) {
    cs[nf] += __shfl_xor(cs[nf], 16);
    cs[nf] += __shfl_xor(cs[nf], 32);
  }
  if (lane < 16)
    #pragma unroll
    for (int nf = 0; nf < 4; ++nf)
      atomicAdd(&Z[b*1024 + n0 + wc*64 + nf*16 + lane], cs[nf]);
}

// ---------------------------------------------------------------------------
// GEMM2: out_mem[d][n] += (sum_k moH[d][k] * E_t[n][k]) / Z[n]
// tile 128d x 128n, BK=64, split-K x4 (ks = z&3), fp32 atomics into zeroed out
// ---------------------------------------------------------------------------
__global__ __launch_bounds__(256) void gemm2_kernel(
    const _Float16* __restrict__ moH, const _Float16* __restrict__ Et,
    const float* __restrict__ Z, float* __restrict__ out) {
  const int zb = blockIdx.z;
  const int b = zb >> 2, ks = zb & 3;
  const int n0 = blockIdx.x*128, d0 = blockIdx.y*128;
  const int tid = threadIdx.x, lane = tid & 63, wid = tid >> 6;
  const int wr = wid >> 1, wc = wid & 1;
  __shared__ __align__(16) _Float16 As[8192], Bs[8192];   // [128][64], swizzled

  const char* Ag = (const char*)(moH + (size_t)b*2097152 + (size_t)d0*4096); // stride 8192B
  const char* Bg = (const char*)(Et  + (size_t)b*4194304 + (size_t)n0*4096);

  f32x4 acc[4][4] = {};
  const int srow = tid >> 3, ssl = tid & 7;

  for (int it = 0; it < 16; ++it) {
    const size_t kb = (size_t)(ks*16 + it) * 128;  // byte offset along k (64 halfs)
    __syncthreads();
    #pragma unroll
    for (int c = 0; c < 4; ++c) {
      const int row = c*32 + srow;
      const int sg  = ssl ^ (row & 7);
      gload16(Ag + (size_t)row*8192 + kb + sg*16, As + c*2048 + wid*512);
      gload16(Bg + (size_t)row*8192 + kb + sg*16, Bs + c*2048 + wid*512);
    }
    __syncthreads();
    #pragma unroll
    for (int kk = 0; kk < 2; ++kk) {
      f16x8 af[4], bf[4];
      #pragma unroll
      for (int mf = 0; mf < 4; ++mf) {
        const int row = wr*64 + mf*16 + (lane & 15);
        const int u   = kk*4 + (lane >> 4);
        af[mf] = *(const f16x8*)&As[row*64 + ((u ^ (row & 7)) << 3)];
      }
      #pragma unroll
      for (int nf = 0; nf < 4; ++nf) {
        const int row = wc*64 + nf*16 + (lane & 15);
        const int u   = kk*4 + (lane >> 4);
        bf[nf] = *(const f16x8*)&Bs[row*64 + ((u ^ (row & 7)) << 3)];
      }
      #pragma unroll
      for (int mf = 0; mf < 4; ++mf)
        #pragma unroll
        for (int nf = 0; nf < 4; ++nf)
          acc[mf][nf] = mfma16h(af[mf], bf[nf], acc[mf][nf]);
    }
  }

  float* ob = out + (size_t)b*1048576;
  #pragma unroll
  for (int nf = 0; nf < 4; ++nf) {
    const int col = n0 + wc*64 + nf*16 + (lane & 15);
    const float rz = 1.0f / Z[b*1024 + col];
    #pragma unroll
    for (int mf = 0; mf < 4; ++mf) {
      const int row = d0 + wr*64 + mf*16 + ((lane >> 4) << 2);
      #pragma unroll
      for (int r = 0; r < 4; ++r)
        atomicAdd(&ob[(size_t)(row + r)*1024 + col], acc[mf][nf][r] * rz);
    }
  }
}

// ---------------------------------------------------------------------------
// finalize (sectioned):
//   blocks [0,8192):    p[k][n] = E_t[n][k] / Z[n]  (64x64 LDS tile transpose)
//   blocks [8192,8704): copy q_out -> out rows 512..1023
// ---------------------------------------------------------------------------
__global__ __launch_bounds__(256) void finalize_kernel(
    const _Float16* __restrict__ Et, const float* __restrict__ Z,
    const float* __restrict__ q_out, float* __restrict__ out,
    float* __restrict__ p)
{
  __shared__ float T[64][65];
  const int bid = blockIdx.x, t = threadIdx.x;
  if (bid < 8192) {
    const int b = bid >> 10, tile = bid & 1023;
    const int kt = tile >> 4, nt = tile & 15;
    const int k0 = kt*64, n0 = nt*64;
    const _Float16* Eb = Et + (size_t)b*4194304;
    {
      const int nl = t >> 2, kc = t & 3;
      #pragma unroll
      for (int u = 0; u < 2; ++u) {
        const int kl = (kc*2 + u)*8;
        f16x8 v = *(const f16x8*)(Eb + (size_t)(n0 + nl)*4096 + k0 + kl);
        #pragma unroll
        for (int j = 0; j < 8; ++j) T[kl + j][nl] = (float)v[j];
      }
    }
    __syncthreads();
    float* pb = p + (size_t)b*4194304;
    {
      const int kr = t >> 2;
      #pragma unroll
      for (int w = 0; w < 4; ++w) {
        const int nq = (t & 3)*4 + w;
        f32x4 z = *(const f32x4*)(Z + b*1024 + n0 + nq*4);
        f32x4 v;
        v[0] = T[kr][nq*4+0]; v[1] = T[kr][nq*4+1];
        v[2] = T[kr][nq*4+2]; v[3] = T[kr][nq*4+3];
        v = v / z;
        *(f32x4*)(pb + (size_t)(k0 + kr)*1024 + n0 + nq*4) = v;
      }
    }
  } else {
    const int NQ4 = 1048576;
    for (int i = (bid - 8192)*256 + t; i < NQ4; i += 512*256) {
      const int b = i >> 17, rem = i & 131071;
      ((f32x4*)out)[(size_t)b*262144 + 131072 + rem] = ((const f32x4*)q_out)[i];
    }
  }
}

extern "C" void kernel_launch(void* const* d_in, const int* in_sizes, int n_in,
                              void* d_out, int out_size, void* d_ws, size_t ws_size,
                              hipStream_t stream) {
  const float* m_in  = (const float*)d_in[0];
  const float* m_out = (const float*)d_in[1];
  const float* q_in  = (const float*)d_in[2];
  const float* q_out = (const float*)d_in[3];
  float* out = (float*)d_out;
  float* p   = out + (size_t)8*1024*1024;        // p region after mem_out

  char* ws = (char*)d_ws;
  size_t off = 0;
  float*    Z   = (float*)(ws + off);    off += 32768;        // 8*1024 f32 (+pad)
  _Float16* moH = (_Float16*)(ws + off); off += 33554432;     // 8*512*4096 fp16
  _Float16* kH  = (_Float16*)(ws + off); off += 16777216;     // 8*4096*128 fp16
  _Float16* qT  = (_Float16*)(ws + off); off += 2097152;      // 8*1024*128 fp16
  _Float16* Et  = (_Float16*)(ws + off);                      // 8*1024*4096 fp16

  prep_kernel<<<2304, 256, 0, stream>>>(m_in, m_out, q_in, out, Z, moH, kH, qT);
  gemm1_kernel<<<dim3(8, 32, 8), 256, 0, stream>>>(kH, qT, Et, Z);
  gemm2_kernel<<<dim3(8, 4, 32), 256, 0, stream>>>(moH, Et, Z, out);
  finalize_kernel<<<8704, 256, 0, stream>>>(Et, Z, q_out, out, p);
}